// Round 7
// baseline (353.779 us; speedup 1.0000x reference)
//
#include <hip/hip_runtime.h>
#include <stdint.h>

#define DIM 256
#define NROWS 8192
#define KTOT 8192

typedef unsigned short u16;
typedef short bf16x8 __attribute__((ext_vector_type(8)));
typedef float f32x4 __attribute__((ext_vector_type(4)));

__device__ __forceinline__ u16 f2bf(float x) {
  uint32_t u = __float_as_uint(x);
  u = (u + 0x7FFFu + ((u >> 16) & 1u)) >> 16;
  return (u16)u;
}

__device__ __forceinline__ float wsum(float v) {
  v += __shfl_xor(v, 32, 64);
  v += __shfl_xor(v, 16, 64);
  v += __shfl_xor(v, 8, 64);
  v += __shfl_xor(v, 4, 64);
  v += __shfl_xor(v, 2, 64);
  v += __shfl_xor(v, 1, 64);
  return v;
}

__device__ __forceinline__ float artanh_c(float x) {
  const float lim = 1.0f - 1e-7f;
  x = fminf(fmaxf(x, -lim), lim);
  return 0.5f * (log1pf(x) - log1pf(-x));
}

// ---------------- K1: mx = x @ W^T  (fp32, 64x64 tiles) ----------------
__global__ __launch_bounds__(256)
void hgcn_k1(const float* __restrict__ x, const float* __restrict__ w,
             float* __restrict__ mx) {
  __shared__ float xs_t[32][64];
  __shared__ float ws_t[32][64];
  int t = threadIdx.x;
  int tx = t & 15, ty = t >> 4;
  int bi = blockIdx.x, bj = blockIdx.y;
  int lr = t >> 2, lc = (t & 3) * 8;
  const float* xp = x + (size_t)(bi * 64 + lr) * DIM + lc;
  const float* wp = w + (size_t)(bj * 64 + lr) * DIM + lc;
  float acc[4][4] = {};
  for (int kb = 0; kb < DIM; kb += 32) {
    float4 a0 = *(const float4*)(xp + kb);
    float4 a1 = *(const float4*)(xp + kb + 4);
    float4 b0 = *(const float4*)(wp + kb);
    float4 b1 = *(const float4*)(wp + kb + 4);
    __syncthreads();
    xs_t[lc + 0][lr] = a0.x; xs_t[lc + 1][lr] = a0.y;
    xs_t[lc + 2][lr] = a0.z; xs_t[lc + 3][lr] = a0.w;
    xs_t[lc + 4][lr] = a1.x; xs_t[lc + 5][lr] = a1.y;
    xs_t[lc + 6][lr] = a1.z; xs_t[lc + 7][lr] = a1.w;
    ws_t[lc + 0][lr] = b0.x; ws_t[lc + 1][lr] = b0.y;
    ws_t[lc + 2][lr] = b0.z; ws_t[lc + 3][lr] = b0.w;
    ws_t[lc + 4][lr] = b1.x; ws_t[lc + 5][lr] = b1.y;
    ws_t[lc + 6][lr] = b1.z; ws_t[lc + 7][lr] = b1.w;
    __syncthreads();
#pragma unroll
    for (int k = 0; k < 32; ++k) {
      float4 xv = *(const float4*)&xs_t[k][ty * 4];
      float4 wv = *(const float4*)&ws_t[k][tx * 4];
      float xr[4] = {xv.x, xv.y, xv.z, xv.w};
      float wr[4] = {wv.x, wv.y, wv.z, wv.w};
#pragma unroll
      for (int ii = 0; ii < 4; ++ii)
#pragma unroll
        for (int jj = 0; jj < 4; ++jj)
          acc[ii][jj] += xr[ii] * wr[jj];
    }
  }
#pragma unroll
  for (int ii = 0; ii < 4; ++ii) {
    float4 o = {acc[ii][0], acc[ii][1], acc[ii][2], acc[ii][3]};
    *(float4*)(mx + (size_t)(bi * 64 + ty * 4 + ii) * DIM + bj * 64 + tx * 4) = o;
  }
}

// ------- K2: hyperbolic chain #1, emits x_tangent^T as bf16 [256][8192] -------
__global__ __launch_bounds__(256)
void hgcn_k2(const float* __restrict__ x, const float* __restrict__ mx,
             const float* __restrict__ bias, u16* __restrict__ xtT) {
  __shared__ u16 xl[64][256];
  const float maxn = 1.0f - 1e-5f;
  int t = threadIdx.x;
  int wave = t >> 6, lane = t & 63;
  int c0 = lane * 4;

  float4 b4 = *(const float4*)(bias + c0);
  float bn2 = wsum(b4.x * b4.x + b4.y * b4.y + b4.z * b4.z + b4.w * b4.w);
  float bn = fmaxf(sqrtf(bn2), 1e-15f);
  float sb = tanhf(bn) / bn;
  float hbx = b4.x * sb, hby = b4.y * sb, hbz = b4.z * sb, hbw = b4.w * sb;
  float ebn2 = wsum(hbx * hbx + hby * hby + hbz * hbz + hbw * hbw);
  float ebn = fmaxf(sqrtf(ebn2), 1e-15f);
  float sp = ebn > maxn ? maxn / ebn : 1.0f;
  hbx *= sp; hby *= sp; hbz *= sp; hbw *= sp;
  float y2 = (ebn * sp) * (ebn * sp);

  for (int rr = 0; rr < 16; ++rr) {
    int iloc = wave * 16 + rr;
    size_t row = (size_t)blockIdx.x * 64 + iloc;
    float4 xv = *(const float4*)(x + row * DIM + c0);
    float4 mv = *(const float4*)(mx + row * DIM + c0);
    float xn2 = wsum(xv.x * xv.x + xv.y * xv.y + xv.z * xv.z + xv.w * xv.w);
    float mxn2 = wsum(mv.x * mv.x + mv.y * mv.y + mv.z * mv.z + mv.w * mv.w);
    int zloc = (mv.x == 0.0f) && (mv.y == 0.0f) && (mv.z == 0.0f) && (mv.w == 0.0f);
    int zrow = __all(zloc);
    float xn = fmaxf(sqrtf(xn2), 1e-15f);
    float mxn = fmaxf(sqrtf(mxn2), 1e-15f);
    float rfac = tanhf(mxn / xn * artanh_c(xn)) / mxn;
    if (zrow) rfac = 0.0f;
    float hx = mv.x * rfac, hy = mv.y * rfac, hz = mv.z * rfac, hw = mv.w * rfac;
    float hn = fmaxf(fabsf(rfac) * mxn, 1e-15f);
    float s1 = hn > maxn ? maxn / hn : 1.0f;
    hx *= s1; hy *= s1; hz *= s1; hw *= s1;
    float x2 = (hn * s1) * (hn * s1);
    float xy = wsum(hx * hbx + hy * hby + hz * hbz + hw * hbw);
    float ca = 1.0f + 2.0f * xy + y2;
    float cb = 1.0f - x2;
    float den = 1.0f + 2.0f * xy + x2 * y2;
    float inv = 1.0f / fmaxf(den, 1e-15f);
    float ox = (ca * hx + cb * hbx) * inv;
    float oy = (ca * hy + cb * hby) * inv;
    float oz = (ca * hz + cb * hbz) * inv;
    float ow = (ca * hw + cb * hbw) * inv;
    float on2 = wsum(ox * ox + oy * oy + oz * oz + ow * ow);
    float on = fmaxf(sqrtf(on2), 1e-15f);
    float s2 = on > maxn ? maxn / on : 1.0f;
    ox *= s2; oy *= s2; oz *= s2; ow *= s2;
    float pn = fmaxf(on * s2, 1e-15f);
    float lf = artanh_c(pn) / pn;
    u16 tmp[4] = {f2bf(ox * lf), f2bf(oy * lf), f2bf(oz * lf), f2bf(ow * lf)};
    *(uint2*)&xl[iloc][c0] = *(const uint2*)tmp;
  }
  __syncthreads();
  int c = t;
  size_t ob = (size_t)c * KTOT + (size_t)blockIdx.x * 64;
  for (int ch = 0; ch < 8; ++ch) {
    u16 tmp[8];
#pragma unroll
    for (int q = 0; q < 8; ++q) tmp[q] = xl[ch * 8 + q][c];
    *(uint4*)(xtT + ob + ch * 8) = *(const uint4*)tmp;
  }
}

// ------- K3: DRAM-granularity-aware. BK=256 (1KB contiguous per adj-row visit). -------
// BM=64, BN=256(all n). Single 32KB LDS B-tile (bf16, 16B-chunk XOR swizzle).
// Bulk-synchronous: stage -> barrier -> compute -> barrier; overlap via ~3 blocks/CU TLP.
// A-frags per-lane from global (xtT slice L2-resident via split-K=8 XCD mapping).
__global__ __launch_bounds__(256, 3)
void hgcn_k3(const float* __restrict__ adj, const u16* __restrict__ xtT,
             float* __restrict__ pbase, int xps_log, int ksize) {
  __shared__ u16 bt[64 * 256];  // [64 m-rows][256 k] bf16; 16B chunk c stored at p = c ^ (row&7)
  int t = threadIdx.x;
  int wave = t >> 6, lane = t & 63;
  int l15 = lane & 15, l4 = lane >> 4;
  int bid = blockIdx.x;
  int xps_m1 = (1 << xps_log) - 1;
  int split = (bid & 7) >> xps_log;
  int sub = (bid & 7) & xps_m1;
  int m_tile = ((bid >> 3) << xps_log) + sub;   // 0..127
  int m0 = m_tile * 64;
  int kbase = split * ksize;
  float* outp = pbase + (size_t)split * ((size_t)NROWS * DIM);
  int n0 = wave * 64;

  const u16* ap[4];
#pragma unroll
  for (int ni = 0; ni < 4; ++ni)
    ap[ni] = xtT + (size_t)(n0 + ni * 16 + l15) * KTOT + kbase + l4 * 8;

  // stage assignment: 4 threads per row, each 64 contiguous floats (256B); row visit = 1KB
  int srow = t >> 2, squad = t & 3;
  const float* sp = adj + (size_t)(m0 + srow) * KTOT + kbase + squad * 64;
  u16* swrow = bt + srow * 256;
  int sxor = srow & 7;

  f32x4 acc[4][4];
#pragma unroll
  for (int i = 0; i < 4; ++i)
#pragma unroll
    for (int j = 0; j < 4; ++j)
      acc[i][j] = (f32x4){0.f, 0.f, 0.f, 0.f};

  for (int kb = 0; kb < ksize; kb += 256) {
    __syncthreads();  // previous compute done reading bt
    // ---- stage: 4 passes x 16 floats -> 2 swizzled bf16 chunks each ----
#pragma unroll
    for (int ps = 0; ps < 4; ++ps) {
      const float* p = sp + kb + ps * 16;
      f32x4 f0 = __builtin_nontemporal_load((const f32x4*)p);
      f32x4 f1 = __builtin_nontemporal_load((const f32x4*)(p + 4));
      f32x4 f2 = __builtin_nontemporal_load((const f32x4*)(p + 8));
      f32x4 f3 = __builtin_nontemporal_load((const f32x4*)(p + 12));
      uint32_t w0, w1, w2, w3, w4, w5, w6, w7;
      asm("v_cvt_pk_bf16_f32 %0, %1, %2" : "=v"(w0) : "v"(f0[0]), "v"(f0[1]));
      asm("v_cvt_pk_bf16_f32 %0, %1, %2" : "=v"(w1) : "v"(f0[2]), "v"(f0[3]));
      asm("v_cvt_pk_bf16_f32 %0, %1, %2" : "=v"(w2) : "v"(f1[0]), "v"(f1[1]));
      asm("v_cvt_pk_bf16_f32 %0, %1, %2" : "=v"(w3) : "v"(f1[2]), "v"(f1[3]));
      asm("v_cvt_pk_bf16_f32 %0, %1, %2" : "=v"(w4) : "v"(f2[0]), "v"(f2[1]));
      asm("v_cvt_pk_bf16_f32 %0, %1, %2" : "=v"(w5) : "v"(f2[2]), "v"(f2[3]));
      asm("v_cvt_pk_bf16_f32 %0, %1, %2" : "=v"(w6) : "v"(f3[0]), "v"(f3[1]));
      asm("v_cvt_pk_bf16_f32 %0, %1, %2" : "=v"(w7) : "v"(f3[2]), "v"(f3[3]));
      int c0 = squad * 8 + ps * 2;
      uint4 d0 = {w0, w1, w2, w3};
      uint4 d1 = {w4, w5, w6, w7};
      *(uint4*)(swrow + ((c0 ^ sxor) * 8)) = d0;
      *(uint4*)(swrow + (((c0 + 1) ^ sxor) * 8)) = d1;
    }
    __syncthreads();  // bt(kb) staged
    // ---- compute: 8 kc sub-steps of 32k ----
#pragma unroll
    for (int kc = 0; kc < 8; ++kc) {
      bf16x8 a[4], b[4];
#pragma unroll
      for (int mi = 0; mi < 4; ++mi) {
        int r = mi * 16 + l15;
        int c = kc * 4 + l4;
        b[mi] = *(const bf16x8*)&bt[r * 256 + ((c ^ (r & 7)) * 8)];
      }
#pragma unroll
      for (int ni = 0; ni < 4; ++ni)
        a[ni] = *(const bf16x8*)(ap[ni] + kb + kc * 32);
#pragma unroll
      for (int ni = 0; ni < 4; ++ni)
#pragma unroll
        for (int mi = 0; mi < 4; ++mi)
          acc[ni][mi] = __builtin_amdgcn_mfma_f32_16x16x32_bf16(a[ni], b[mi], acc[ni][mi], 0, 0, 0);
    }
  }

  // epilogue: D[n][m] -> partial[m][n]  (mapping verified r2-r6)
#pragma unroll
  for (int ni = 0; ni < 4; ++ni)
#pragma unroll
    for (int mi = 0; mi < 4; ++mi) {
      int n = n0 + ni * 16 + l4 * 4;
      int m = m0 + mi * 16 + l15;
      *(f32x4*)(outp + (size_t)m * DIM + n) = acc[ni][mi];
    }
}

// ---------------- K4: sum nsplit partials + hyperbolic chain #2 -> d_out ----------------
__global__ __launch_bounds__(256)
void hgcn_k4(const float* __restrict__ pbase, size_t pstride, int nsplit,
             float* __restrict__ out) {
  const float maxn = 1.0f - 1e-5f;
  int t = threadIdx.x;
  int wave = t >> 6, lane = t & 63;
  size_t row = (size_t)blockIdx.x * 4 + wave;
  int c0 = lane * 4;
  size_t off = row * DIM + c0;
  float sx = 0.f, sy = 0.f, sz = 0.f, sw = 0.f;
  for (int i = 0; i < nsplit; ++i) {
    float4 v = *(const float4*)(pbase + (size_t)i * pstride + off);
    sx += v.x; sy += v.y; sz += v.z; sw += v.w;
  }
  float un2 = wsum(sx * sx + sy * sy + sz * sz + sw * sw);
  float un = fmaxf(sqrtf(un2), 1e-15f);
  float t1 = tanhf(un) / un;
  float hx = sx * t1, hy = sy * t1, hz = sz * t1, hw = sw * t1;
  float hn = fmaxf(fabsf(t1) * un, 1e-15f);
  float s1 = hn > maxn ? maxn / hn : 1.0f;
  hx *= s1; hy *= s1; hz *= s1; hw *= s1;
  float pn = fmaxf(hn * s1, 1e-15f);
  float lf = artanh_c(pn) / pn;
  float rx = fmaxf(hx * lf, 0.0f), ry = fmaxf(hy * lf, 0.0f);
  float rz = fmaxf(hz * lf, 0.0f), rw = fmaxf(hw * lf, 0.0f);
  float rn2 = wsum(rx * rx + ry * ry + rz * rz + rw * rw);
  float rn = fmaxf(sqrtf(rn2), 1e-15f);
  float t2 = tanhf(rn) / rn;
  float ox = rx * t2, oy = ry * t2, oz = rz * t2, ow = rw * t2;
  float on = fmaxf(fabsf(t2) * rn, 1e-15f);
  float s3 = on > maxn ? maxn / on : 1.0f;
  float4 o = {ox * s3, oy * s3, oz * s3, ow * s3};
  *(float4*)(out + off) = o;
}

extern "C" void kernel_launch(void* const* d_in, const int* in_sizes, int n_in,
                              void* d_out, int out_size, void* d_ws, size_t ws_size,
                              hipStream_t stream) {
  const float* x = (const float*)d_in[0];
  const float* adj = (const float*)d_in[1];
  const float* wgt = (const float*)d_in[2];
  const float* bias = (const float*)d_in[3];
  float* out = (float*)d_out;
  char* ws = (char*)d_ws;
  float* mx = (float*)ws;                      // [0, 8MB)
  u16* xtT = (u16*)(ws + (8u << 20));          // [8MB, 12MB)
  float* pbase = (float*)(ws + (12u << 20));   // [12MB, 12MB + ksplit*8MB)

  const size_t PBYTES = (size_t)NROWS * DIM * 4;   // 8MB per partial
  const size_t BASE = (size_t)12 << 20;
  int ksplit = (ws_size >= BASE + 8 * PBYTES) ? 8
             : (ws_size >= BASE + 4 * PBYTES) ? 4 : 2;
  int xps_log = (ksplit == 8) ? 0 : (ksplit == 4) ? 1 : 2;
  int ksize = KTOT / ksplit;

  hipLaunchKernelGGL(hgcn_k1, dim3(128, 4), dim3(256), 0, stream, x, wgt, mx);
  hipLaunchKernelGGL(hgcn_k2, dim3(128), dim3(256), 0, stream, x, mx, bias, xtT);
  hipLaunchKernelGGL(hgcn_k3, dim3(128 * ksplit), dim3(256), 0, stream,
                     adj, xtT, pbase, xps_log, ksize);
  hipLaunchKernelGGL(hgcn_k4, dim3(2048), dim3(256), 0, stream,
                     pbase, (size_t)NROWS * DIM, ksplit, out);
}

// Round 8
// 233.160 us; speedup vs baseline: 1.5173x; 1.5173x over previous
//
#include <hip/hip_runtime.h>
#include <stdint.h>

#define DIM 256
#define NROWS 8192
#define KTOT 8192
#define KSPLIT 4
#define KSZ 2048  // k per split

typedef unsigned short u16;
typedef short bf16x8 __attribute__((ext_vector_type(8)));
typedef float f32x4 __attribute__((ext_vector_type(4)));

__device__ __forceinline__ u16 f2bf(float x) {
  uint32_t u = __float_as_uint(x);
  u = (u + 0x7FFFu + ((u >> 16) & 1u)) >> 16;
  return (u16)u;
}

__device__ __forceinline__ float wsum(float v) {
  v += __shfl_xor(v, 32, 64);
  v += __shfl_xor(v, 16, 64);
  v += __shfl_xor(v, 8, 64);
  v += __shfl_xor(v, 4, 64);
  v += __shfl_xor(v, 2, 64);
  v += __shfl_xor(v, 1, 64);
  return v;
}

__device__ __forceinline__ float artanh_c(float x) {
  const float lim = 1.0f - 1e-7f;
  x = fminf(fmaxf(x, -lim), lim);
  return 0.5f * (log1pf(x) - log1pf(-x));
}

// ---------------- K1: mx = x @ W^T  (fp32, 64x64 tiles) ----------------
__global__ __launch_bounds__(256)
void hgcn_k1(const float* __restrict__ x, const float* __restrict__ w,
             float* __restrict__ mx) {
  __shared__ float xs_t[32][64];
  __shared__ float ws_t[32][64];
  int t = threadIdx.x;
  int tx = t & 15, ty = t >> 4;
  int bi = blockIdx.x, bj = blockIdx.y;
  int lr = t >> 2, lc = (t & 3) * 8;
  const float* xp = x + (size_t)(bi * 64 + lr) * DIM + lc;
  const float* wp = w + (size_t)(bj * 64 + lr) * DIM + lc;
  float acc[4][4] = {};
  for (int kb = 0; kb < DIM; kb += 32) {
    float4 a0 = *(const float4*)(xp + kb);
    float4 a1 = *(const float4*)(xp + kb + 4);
    float4 b0 = *(const float4*)(wp + kb);
    float4 b1 = *(const float4*)(wp + kb + 4);
    __syncthreads();
    xs_t[lc + 0][lr] = a0.x; xs_t[lc + 1][lr] = a0.y;
    xs_t[lc + 2][lr] = a0.z; xs_t[lc + 3][lr] = a0.w;
    xs_t[lc + 4][lr] = a1.x; xs_t[lc + 5][lr] = a1.y;
    xs_t[lc + 6][lr] = a1.z; xs_t[lc + 7][lr] = a1.w;
    ws_t[lc + 0][lr] = b0.x; ws_t[lc + 1][lr] = b0.y;
    ws_t[lc + 2][lr] = b0.z; ws_t[lc + 3][lr] = b0.w;
    ws_t[lc + 4][lr] = b1.x; ws_t[lc + 5][lr] = b1.y;
    ws_t[lc + 6][lr] = b1.z; ws_t[lc + 7][lr] = b1.w;
    __syncthreads();
#pragma unroll
    for (int k = 0; k < 32; ++k) {
      float4 xv = *(const float4*)&xs_t[k][ty * 4];
      float4 wv = *(const float4*)&ws_t[k][tx * 4];
      float xr[4] = {xv.x, xv.y, xv.z, xv.w};
      float wr[4] = {wv.x, wv.y, wv.z, wv.w};
#pragma unroll
      for (int ii = 0; ii < 4; ++ii)
#pragma unroll
        for (int jj = 0; jj < 4; ++jj)
          acc[ii][jj] += xr[ii] * wr[jj];
    }
  }
#pragma unroll
  for (int ii = 0; ii < 4; ++ii) {
    float4 o = {acc[ii][0], acc[ii][1], acc[ii][2], acc[ii][3]};
    *(float4*)(mx + (size_t)(bi * 64 + ty * 4 + ii) * DIM + bj * 64 + tx * 4) = o;
  }
}

// ------- K2: hyperbolic chain #1 -> x_tangent^T bf16, SPLIT-PACKED layout -------
// xtTs[split][256][KSZ]: per-split slice is 1MB contiguous (L2-set friendly).
__global__ __launch_bounds__(256)
void hgcn_k2(const float* __restrict__ x, const float* __restrict__ mx,
             const float* __restrict__ bias, u16* __restrict__ xtTs) {
  __shared__ u16 xl[64][256];
  const float maxn = 1.0f - 1e-5f;
  int t = threadIdx.x;
  int wave = t >> 6, lane = t & 63;
  int c0 = lane * 4;

  float4 b4 = *(const float4*)(bias + c0);
  float bn2 = wsum(b4.x * b4.x + b4.y * b4.y + b4.z * b4.z + b4.w * b4.w);
  float bn = fmaxf(sqrtf(bn2), 1e-15f);
  float sb = tanhf(bn) / bn;
  float hbx = b4.x * sb, hby = b4.y * sb, hbz = b4.z * sb, hbw = b4.w * sb;
  float ebn2 = wsum(hbx * hbx + hby * hby + hbz * hbz + hbw * hbw);
  float ebn = fmaxf(sqrtf(ebn2), 1e-15f);
  float sp = ebn > maxn ? maxn / ebn : 1.0f;
  hbx *= sp; hby *= sp; hbz *= sp; hbw *= sp;
  float y2 = (ebn * sp) * (ebn * sp);

  for (int rr = 0; rr < 16; ++rr) {
    int iloc = wave * 16 + rr;
    size_t row = (size_t)blockIdx.x * 64 + iloc;
    float4 xv = *(const float4*)(x + row * DIM + c0);
    float4 mv = *(const float4*)(mx + row * DIM + c0);
    float xn2 = wsum(xv.x * xv.x + xv.y * xv.y + xv.z * xv.z + xv.w * xv.w);
    float mxn2 = wsum(mv.x * mv.x + mv.y * mv.y + mv.z * mv.z + mv.w * mv.w);
    int zloc = (mv.x == 0.0f) && (mv.y == 0.0f) && (mv.z == 0.0f) && (mv.w == 0.0f);
    int zrow = __all(zloc);
    float xn = fmaxf(sqrtf(xn2), 1e-15f);
    float mxn = fmaxf(sqrtf(mxn2), 1e-15f);
    float rfac = tanhf(mxn / xn * artanh_c(xn)) / mxn;
    if (zrow) rfac = 0.0f;
    float hx = mv.x * rfac, hy = mv.y * rfac, hz = mv.z * rfac, hw = mv.w * rfac;
    float hn = fmaxf(fabsf(rfac) * mxn, 1e-15f);
    float s1 = hn > maxn ? maxn / hn : 1.0f;
    hx *= s1; hy *= s1; hz *= s1; hw *= s1;
    float x2 = (hn * s1) * (hn * s1);
    float xy = wsum(hx * hbx + hy * hby + hz * hbz + hw * hbw);
    float ca = 1.0f + 2.0f * xy + y2;
    float cb = 1.0f - x2;
    float den = 1.0f + 2.0f * xy + x2 * y2;
    float inv = 1.0f / fmaxf(den, 1e-15f);
    float ox = (ca * hx + cb * hbx) * inv;
    float oy = (ca * hy + cb * hby) * inv;
    float oz = (ca * hz + cb * hbz) * inv;
    float ow = (ca * hw + cb * hbw) * inv;
    float on2 = wsum(ox * ox + oy * oy + oz * oz + ow * ow);
    float on = fmaxf(sqrtf(on2), 1e-15f);
    float s2 = on > maxn ? maxn / on : 1.0f;
    ox *= s2; oy *= s2; oz *= s2; ow *= s2;
    float pn = fmaxf(on * s2, 1e-15f);
    float lf = artanh_c(pn) / pn;
    u16 tmp[4] = {f2bf(ox * lf), f2bf(oy * lf), f2bf(oz * lf), f2bf(ow * lf)};
    *(uint2*)&xl[iloc][c0] = *(const uint2*)tmp;
  }
  __syncthreads();
  int c = t;
  int split = blockIdx.x >> 5;                 // (blockIdx*64)/KSZ
  int koff = (blockIdx.x & 31) * 64;           // within split
  size_t ob = (size_t)split * (256 * KSZ) + (size_t)c * KSZ + koff;
  for (int ch = 0; ch < 8; ++ch) {
    u16 tmp[8];
#pragma unroll
    for (int q = 0; q < 8; ++q) tmp[q] = xl[ch * 8 + q][c];
    *(uint4*)(xtTs + ob + ch * 8) = *(const uint4*)tmp;
  }
}

// ------- K3: BM=32, ksplit=4. Whole split-tile (32 rows x 8KB adj) staged once -------
// into 128KB LDS as bf16. Adj read = 8KB-contiguous runs per row (DRAM-friendly).
// Then one barrier + pure-LDS/L2 compute. 1 block/CU.
__global__ __launch_bounds__(256, 1)
void hgcn_k3(const float* __restrict__ adj, const u16* __restrict__ xtTs,
             float* __restrict__ pbase) {
  __shared__ u16 bt[32 * KSZ];  // [32 rows][2048 bf16], 16B-chunk pos = c ^ (r&7); 128KB
  int t = threadIdx.x;
  int wave = t >> 6, lane = t & 63;
  int l15 = lane & 15, l4 = lane >> 4;
  int bid = blockIdx.x;
  int e = bid & 7;
  int split = e >> 1;                       // 2 XCDs per split
  int mt = (bid >> 3) * 2 + (e & 1);        // 0..255
  int m0 = mt * 32;
  int kbase = split * KSZ;
  float* outp = pbase + (size_t)split * ((size_t)NROWS * DIM);
  int n0 = wave * 64;

  // ---- stage: wave w handles rows w*8..w*8+7, 4 passes x 2KB per row ----
  {
    const float* base = adj + (size_t)(m0 + wave * 8) * KTOT + kbase + lane * 8;
    float4 L[4][2];
#pragma unroll
    for (int pi = 0; pi < 4; ++pi) {
      const float* p = base + pi * 512;   // iter pi: r-off 0, pass pi
      L[pi][0] = ((const float4*)p)[0];
      L[pi][1] = ((const float4*)p)[1];
    }
#pragma unroll
    for (int i = 0; i < 32; ++i) {
      float4 a0 = L[i & 3][0], a1 = L[i & 3][1];
      uint32_t w0, w1, w2, w3;
      asm("v_cvt_pk_bf16_f32 %0, %1, %2" : "=v"(w0) : "v"(a0.x), "v"(a0.y));
      asm("v_cvt_pk_bf16_f32 %0, %1, %2" : "=v"(w1) : "v"(a0.z), "v"(a0.w));
      asm("v_cvt_pk_bf16_f32 %0, %1, %2" : "=v"(w2) : "v"(a1.x), "v"(a1.y));
      asm("v_cvt_pk_bf16_f32 %0, %1, %2" : "=v"(w3) : "v"(a1.z), "v"(a1.w));
      if (i + 4 < 32) {
        const float* p = base + ((i + 4) >> 2) * KTOT + ((i + 4) & 3) * 512;
        L[i & 3][0] = ((const float4*)p)[0];
        L[i & 3][1] = ((const float4*)p)[1];
      }
      int rl = i >> 2;                     // row within wave's 8 (== r&7)
      int c = (i & 3) * 64 + lane;         // chunk 0..255
      uint4 d = {w0, w1, w2, w3};
      *(uint4*)((char*)bt + (size_t)(wave * 8 + rl) * 4096 + ((c ^ rl) * 16)) = d;
    }
  }
  __syncthreads();

  // ---- compute: 64 kc steps; A from L2-resident packed xtTs, B from LDS ----
  const u16* xbase = xtTs + (size_t)split * (256 * KSZ);
  const u16* ap[4];
#pragma unroll
  for (int ni = 0; ni < 4; ++ni)
    ap[ni] = xbase + (size_t)(n0 + ni * 16 + l15) * KSZ + l4 * 8;

  f32x4 acc[4][2];
#pragma unroll
  for (int i = 0; i < 4; ++i)
#pragma unroll
    for (int j = 0; j < 2; ++j)
      acc[i][j] = (f32x4){0.f, 0.f, 0.f, 0.f};

#pragma unroll 2
  for (int kc = 0; kc < 64; ++kc) {
    bf16x8 a[4], b[2];
#pragma unroll
    for (int mi = 0; mi < 2; ++mi) {
      int r = mi * 16 + l15;
      int c = kc * 4 + l4;
      b[mi] = *(const bf16x8*)((const char*)bt + (size_t)r * 4096 + ((c ^ (r & 7)) * 16));
    }
#pragma unroll
    for (int ni = 0; ni < 4; ++ni)
      a[ni] = *(const bf16x8*)(ap[ni] + kc * 32);
#pragma unroll
    for (int ni = 0; ni < 4; ++ni)
#pragma unroll
      for (int mi = 0; mi < 2; ++mi)
        acc[ni][mi] = __builtin_amdgcn_mfma_f32_16x16x32_bf16(a[ni], b[mi], acc[ni][mi], 0, 0, 0);
  }

  // epilogue: D[n][m] -> partial[m][n]  (mapping verified r2-r7)
#pragma unroll
  for (int ni = 0; ni < 4; ++ni)
#pragma unroll
    for (int mi = 0; mi < 2; ++mi) {
      int n = n0 + ni * 16 + l4 * 4;
      int m = m0 + mi * 16 + l15;
      *(f32x4*)(outp + (size_t)m * DIM + n) = acc[ni][mi];
    }
}

// ---------------- K4: sum 4 partials + hyperbolic chain #2 -> d_out ----------------
__global__ __launch_bounds__(256)
void hgcn_k4(const float* __restrict__ pbase, size_t pstride,
             float* __restrict__ out) {
  const float maxn = 1.0f - 1e-5f;
  int t = threadIdx.x;
  int wave = t >> 6, lane = t & 63;
  size_t row = (size_t)blockIdx.x * 4 + wave;
  int c0 = lane * 4;
  size_t off = row * DIM + c0;
  float sx = 0.f, sy = 0.f, sz = 0.f, sw = 0.f;
#pragma unroll
  for (int i = 0; i < KSPLIT; ++i) {
    float4 v = *(const float4*)(pbase + (size_t)i * pstride + off);
    sx += v.x; sy += v.y; sz += v.z; sw += v.w;
  }
  float un2 = wsum(sx * sx + sy * sy + sz * sz + sw * sw);
  float un = fmaxf(sqrtf(un2), 1e-15f);
  float t1 = tanhf(un) / un;
  float hx = sx * t1, hy = sy * t1, hz = sz * t1, hw = sw * t1;
  float hn = fmaxf(fabsf(t1) * un, 1e-15f);
  float s1 = hn > maxn ? maxn / hn : 1.0f;
  hx *= s1; hy *= s1; hz *= s1; hw *= s1;
  float pn = fmaxf(hn * s1, 1e-15f);
  float lf = artanh_c(pn) / pn;
  float rx = fmaxf(hx * lf, 0.0f), ry = fmaxf(hy * lf, 0.0f);
  float rz = fmaxf(hz * lf, 0.0f), rw = fmaxf(hw * lf, 0.0f);
  float rn2 = wsum(rx * rx + ry * ry + rz * rz + rw * rw);
  float rn = fmaxf(sqrtf(rn2), 1e-15f);
  float t2 = tanhf(rn) / rn;
  float ox = rx * t2, oy = ry * t2, oz = rz * t2, ow = rw * t2;
  float on = fmaxf(fabsf(t2) * rn, 1e-15f);
  float s3 = on > maxn ? maxn / on : 1.0f;
  float4 o = {ox * s3, oy * s3, oz * s3, ow * s3};
  *(float4*)(out + off) = o;
}

extern "C" void kernel_launch(void* const* d_in, const int* in_sizes, int n_in,
                              void* d_out, int out_size, void* d_ws, size_t ws_size,
                              hipStream_t stream) {
  const float* x = (const float*)d_in[0];
  const float* adj = (const float*)d_in[1];
  const float* wgt = (const float*)d_in[2];
  const float* bias = (const float*)d_in[3];
  float* out = (float*)d_out;
  char* ws = (char*)d_ws;
  float* mx = (float*)ws;                      // [0, 8MB)
  u16* xtTs = (u16*)(ws + (8u << 20));         // [8MB, 12MB) split-packed
  float* pbase = (float*)(ws + (12u << 20));   // [12MB, 44MB): 4 partials x 8MB

  hipLaunchKernelGGL(hgcn_k1, dim3(128, 4), dim3(256), 0, stream, x, wgt, mx);
  hipLaunchKernelGGL(hgcn_k2, dim3(128), dim3(256), 0, stream, x, mx, bias, xtTs);
  hipLaunchKernelGGL(hgcn_k3, dim3(1024), dim3(256), 0, stream, adj, xtTs, pbase);
  hipLaunchKernelGGL(hgcn_k4, dim3(2048), dim3(256), 0, stream,
                     pbase, (size_t)NROWS * DIM, out);
}

// Round 9
// 186.879 us; speedup vs baseline: 1.8931x; 1.2477x over previous
//
#include <hip/hip_runtime.h>
#include <stdint.h>

#define DIM 256
#define NROWS 8192
#define KTOT 8192
#define KSPLIT 4
#define KSZ 2048

typedef unsigned short u16;
typedef short bf16x8 __attribute__((ext_vector_type(8)));
typedef float f32x4 __attribute__((ext_vector_type(4)));

__device__ __forceinline__ u16 f2bf(float x) {
  uint32_t u = __float_as_uint(x);
  u = (u + 0x7FFFu + ((u >> 16) & 1u)) >> 16;
  return (u16)u;
}

__device__ __forceinline__ float wsum(float v) {
  v += __shfl_xor(v, 32, 64);
  v += __shfl_xor(v, 16, 64);
  v += __shfl_xor(v, 8, 64);
  v += __shfl_xor(v, 4, 64);
  v += __shfl_xor(v, 2, 64);
  v += __shfl_xor(v, 1, 64);
  return v;
}

__device__ __forceinline__ float artanh_c(float x) {
  const float lim = 1.0f - 1e-7f;
  x = fminf(fmaxf(x, -lim), lim);
  return 0.5f * (log1pf(x) - log1pf(-x));
}

// ---------------- K1: mx = x @ W^T  (fp32, 64x64 tiles) ----------------
__global__ __launch_bounds__(256)
void hgcn_k1(const float* __restrict__ x, const float* __restrict__ w,
             float* __restrict__ mx) {
  __shared__ float xs_t[32][64];
  __shared__ float ws_t[32][64];
  int t = threadIdx.x;
  int tx = t & 15, ty = t >> 4;
  int bi = blockIdx.x, bj = blockIdx.y;
  int lr = t >> 2, lc = (t & 3) * 8;
  const float* xp = x + (size_t)(bi * 64 + lr) * DIM + lc;
  const float* wp = w + (size_t)(bj * 64 + lr) * DIM + lc;
  float acc[4][4] = {};
  for (int kb = 0; kb < DIM; kb += 32) {
    float4 a0 = *(const float4*)(xp + kb);
    float4 a1 = *(const float4*)(xp + kb + 4);
    float4 b0 = *(const float4*)(wp + kb);
    float4 b1 = *(const float4*)(wp + kb + 4);
    __syncthreads();
    xs_t[lc + 0][lr] = a0.x; xs_t[lc + 1][lr] = a0.y;
    xs_t[lc + 2][lr] = a0.z; xs_t[lc + 3][lr] = a0.w;
    xs_t[lc + 4][lr] = a1.x; xs_t[lc + 5][lr] = a1.y;
    xs_t[lc + 6][lr] = a1.z; xs_t[lc + 7][lr] = a1.w;
    ws_t[lc + 0][lr] = b0.x; ws_t[lc + 1][lr] = b0.y;
    ws_t[lc + 2][lr] = b0.z; ws_t[lc + 3][lr] = b0.w;
    ws_t[lc + 4][lr] = b1.x; ws_t[lc + 5][lr] = b1.y;
    ws_t[lc + 6][lr] = b1.z; ws_t[lc + 7][lr] = b1.w;
    __syncthreads();
#pragma unroll
    for (int k = 0; k < 32; ++k) {
      float4 xv = *(const float4*)&xs_t[k][ty * 4];
      float4 wv = *(const float4*)&ws_t[k][tx * 4];
      float xr[4] = {xv.x, xv.y, xv.z, xv.w};
      float wr[4] = {wv.x, wv.y, wv.z, wv.w};
#pragma unroll
      for (int ii = 0; ii < 4; ++ii)
#pragma unroll
        for (int jj = 0; jj < 4; ++jj)
          acc[ii][jj] += xr[ii] * wr[jj];
    }
  }
#pragma unroll
  for (int ii = 0; ii < 4; ++ii) {
    float4 o = {acc[ii][0], acc[ii][1], acc[ii][2], acc[ii][3]};
    *(float4*)(mx + (size_t)(bi * 64 + ty * 4 + ii) * DIM + bj * 64 + tx * 4) = o;
  }
}

// ------- K2: hyperbolic chain #1 -> xtTp[split][kblk][256 n][64 k] bf16, swizzle baked -------
__global__ __launch_bounds__(256)
void hgcn_k2(const float* __restrict__ x, const float* __restrict__ mx,
             const float* __restrict__ bias, u16* __restrict__ xtTp) {
  __shared__ u16 xl[64][256];
  const float maxn = 1.0f - 1e-5f;
  int t = threadIdx.x;
  int wave = t >> 6, lane = t & 63;
  int c0 = lane * 4;

  float4 b4 = *(const float4*)(bias + c0);
  float bn2 = wsum(b4.x * b4.x + b4.y * b4.y + b4.z * b4.z + b4.w * b4.w);
  float bn = fmaxf(sqrtf(bn2), 1e-15f);
  float sb = tanhf(bn) / bn;
  float hbx = b4.x * sb, hby = b4.y * sb, hbz = b4.z * sb, hbw = b4.w * sb;
  float ebn2 = wsum(hbx * hbx + hby * hby + hbz * hbz + hbw * hbw);
  float ebn = fmaxf(sqrtf(ebn2), 1e-15f);
  float sp = ebn > maxn ? maxn / ebn : 1.0f;
  hbx *= sp; hby *= sp; hbz *= sp; hbw *= sp;
  float y2 = (ebn * sp) * (ebn * sp);

  for (int rr = 0; rr < 16; ++rr) {
    int iloc = wave * 16 + rr;
    size_t row = (size_t)blockIdx.x * 64 + iloc;
    float4 xv = *(const float4*)(x + row * DIM + c0);
    float4 mv = *(const float4*)(mx + row * DIM + c0);
    float xn2 = wsum(xv.x * xv.x + xv.y * xv.y + xv.z * xv.z + xv.w * xv.w);
    float mxn2 = wsum(mv.x * mv.x + mv.y * mv.y + mv.z * mv.z + mv.w * mv.w);
    int zloc = (mv.x == 0.0f) && (mv.y == 0.0f) && (mv.z == 0.0f) && (mv.w == 0.0f);
    int zrow = __all(zloc);
    float xn = fmaxf(sqrtf(xn2), 1e-15f);
    float mxn = fmaxf(sqrtf(mxn2), 1e-15f);
    float rfac = tanhf(mxn / xn * artanh_c(xn)) / mxn;
    if (zrow) rfac = 0.0f;
    float hx = mv.x * rfac, hy = mv.y * rfac, hz = mv.z * rfac, hw = mv.w * rfac;
    float hn = fmaxf(fabsf(rfac) * mxn, 1e-15f);
    float s1 = hn > maxn ? maxn / hn : 1.0f;
    hx *= s1; hy *= s1; hz *= s1; hw *= s1;
    float x2 = (hn * s1) * (hn * s1);
    float xy = wsum(hx * hbx + hy * hby + hz * hbz + hw * hbw);
    float ca = 1.0f + 2.0f * xy + y2;
    float cb = 1.0f - x2;
    float den = 1.0f + 2.0f * xy + x2 * y2;
    float inv = 1.0f / fmaxf(den, 1e-15f);
    float ox = (ca * hx + cb * hbx) * inv;
    float oy = (ca * hy + cb * hby) * inv;
    float oz = (ca * hz + cb * hbz) * inv;
    float ow = (ca * hw + cb * hbw) * inv;
    float on2 = wsum(ox * ox + oy * oy + oz * oz + ow * ow);
    float on = fmaxf(sqrtf(on2), 1e-15f);
    float s2 = on > maxn ? maxn / on : 1.0f;
    ox *= s2; oy *= s2; oz *= s2; ow *= s2;
    float pn = fmaxf(on * s2, 1e-15f);
    float lf = artanh_c(pn) / pn;
    u16 tmp[4] = {f2bf(ox * lf), f2bf(oy * lf), f2bf(oz * lf), f2bf(ow * lf)};
    *(uint2*)&xl[iloc][c0] = *(const uint2*)tmp;
  }
  __syncthreads();
  int c = t;
  int split = blockIdx.x >> 5;
  int kblk = blockIdx.x & 31;
  size_t ob = ((size_t)(split * 32 + kblk) * 256 + c) * 64;
  for (int q = 0; q < 8; ++q) {
    u16 tmp[8];
#pragma unroll
    for (int i = 0; i < 8; ++i) tmp[i] = xl[q * 8 + i][c];
    *(uint4*)(xtTp + ob + (size_t)((q ^ (c & 7)) * 8)) = *(const uint4*)tmp;
  }
}

// ------- K3a: adj fp32 -> adjT[split][kblk][8192 m][64 k] bf16, swizzle baked -------
// Reads: 8KB-sequential per row, coalesced, nontemporal. Writes: 2KB slabs.
__global__ __launch_bounds__(256, 2)
void hgcn_k3a(const float* __restrict__ adj, u16* __restrict__ adjT) {
  __shared__ u16 sbuf[16 * 2048];  // 64KB; row r: 256 chunks of 16B, low-3 XOR (r&7)
  int t = threadIdx.x;
  int bid = blockIdx.x;            // 512 = 128 mchunk x 4 split
  int split = bid & 3;
  int m0 = (bid >> 2) * 64;
  int kbase = split * KSZ;

  for (int pass = 0; pass < 4; ++pass) {
    int mrow0 = m0 + pass * 16;
    // ---- read+cvt: 16 rows x 2048 fp32, fully sequential per row ----
#pragma unroll 4
    for (int j = 0; j < 32; ++j) {
      int f = j * 256 + t;            // float4 index within [16][512]
      int r = f >> 9, p = f & 511;
      f32x4 v = __builtin_nontemporal_load(
          (const f32x4*)(adj + (size_t)(mrow0 + r) * KTOT + kbase + p * 4));
      uint32_t w0, w1;
      asm("v_cvt_pk_bf16_f32 %0, %1, %2" : "=v"(w0) : "v"(v[0]), "v"(v[1]));
      asm("v_cvt_pk_bf16_f32 %0, %1, %2" : "=v"(w1) : "v"(v[2]), "v"(v[3]));
      int c = p >> 1, h = p & 1;
      int sc = (c & ~7) | ((c & 7) ^ (r & 7));
      uint2 d = {w0, w1};
      *(uint2*)((char*)sbuf + r * 4096 + sc * 16 + h * 8) = d;
    }
    __syncthreads();
    // ---- write-out: 32 kblk-slabs of [16 m][64 k] (2KB contiguous each) ----
#pragma unroll 4
    for (int j2 = 0; j2 < 16; ++j2) {
      int w = j2 * 256 + t;           // uint4 index
      int kb = w >> 7, u = w & 127;
      int r = u >> 3, q = u & 7;
      uint4 d = *(const uint4*)((const char*)sbuf + r * 4096 + kb * 128 + q * 16);
      size_t dst = ((size_t)(split * 32 + kb) * NROWS + (mrow0 + r)) * 64 + q * 8;
      *(uint4*)(adjT + dst) = d;
    }
    __syncthreads();
  }
}

// ------- K3b: GEMM, all-contiguous tiles via global_load_lds, counted vmcnt -------
#define K3_WAITV(N) { asm volatile("s_waitcnt vmcnt(" #N ")" ::: "memory"); __builtin_amdgcn_sched_barrier(0); }

__device__ __forceinline__ void k3b_stage(const u16* __restrict__ aRegion,
                                          const u16* __restrict__ bRegion,
                                          u16* __restrict__ lA, u16* __restrict__ lB,
                                          int wave, int lane) {
#pragma unroll
  for (int jj = 0; jj < 4; ++jj) {
    int j = wave * 4 + jj;
    __builtin_amdgcn_global_load_lds(
        (const __attribute__((address_space(1))) void*)(aRegion + j * 512 + lane * 8),
        (__attribute__((address_space(3))) void*)(lA + j * 512), 16, 0, 0);
  }
#pragma unroll
  for (int jj = 0; jj < 2; ++jj) {
    int j = wave * 2 + jj;
    __builtin_amdgcn_global_load_lds(
        (const __attribute__((address_space(1))) void*)(bRegion + j * 512 + lane * 8),
        (__attribute__((address_space(3))) void*)(lB + j * 512), 16, 0, 0);
  }
}

__device__ __forceinline__ void k3b_compute(const u16* __restrict__ lA, const u16* __restrict__ lB,
                                            f32x4 (&acc)[4][4], int wm, int wn, int l15, int l4) {
  __builtin_amdgcn_s_setprio(1);
#pragma unroll
  for (int kc = 0; kc < 2; ++kc) {
    bf16x8 a[4], b[4];
#pragma unroll
    for (int ni = 0; ni < 4; ++ni) {
      int r = wn * 64 + ni * 16 + l15;
      a[ni] = *(const bf16x8*)&lA[r * 64 + ((kc * 4 + l4) ^ (r & 7)) * 8];
    }
#pragma unroll
    for (int mi = 0; mi < 4; ++mi) {
      int r = wm * 64 + mi * 16 + l15;
      b[mi] = *(const bf16x8*)&lB[r * 64 + ((kc * 4 + l4) ^ (r & 7)) * 8];
    }
#pragma unroll
    for (int ni = 0; ni < 4; ++ni)
#pragma unroll
      for (int mi = 0; mi < 4; ++mi)
        acc[ni][mi] = __builtin_amdgcn_mfma_f32_16x16x32_bf16(a[ni], b[mi], acc[ni][mi], 0, 0, 0);
  }
  __builtin_amdgcn_s_setprio(0);
}

__global__ __launch_bounds__(512, 1)
void hgcn_k3b(const u16* __restrict__ adjT, const u16* __restrict__ xtTp,
              float* __restrict__ pbase) {
  __shared__ u16 lA[2][256 * 64];  // 2 x 32KB
  __shared__ u16 lB[2][128 * 64];  // 2 x 16KB
  int t = threadIdx.x;
  int wave = t >> 6, lane = t & 63;
  int l15 = lane & 15, l4 = lane >> 4;
  int wn = wave & 3, wm = wave >> 2;
  int bid = blockIdx.x;  // 256 = 64 mt x 4 split, XCD-mapped
  int e = bid & 7;
  int split = e >> 1;
  int mt = (bid >> 3) * 2 + (e & 1);
  int m0 = mt * 128;
  float* outp = pbase + (size_t)split * ((size_t)NROWS * DIM);

  const u16* aBase = xtTp + (size_t)(split * 32) * (256 * 64);
  const u16* bBase = adjT + ((size_t)(split * 32) * NROWS + m0) * 64;

  f32x4 acc[4][4];
#pragma unroll
  for (int i = 0; i < 4; ++i)
#pragma unroll
    for (int j = 0; j < 4; ++j)
      acc[i][j] = (f32x4){0.f, 0.f, 0.f, 0.f};

  k3b_stage(aBase, bBase, lA[0], lB[0], wave, lane);
  for (int s = 0; s < 32; ++s) {
    int cur = s & 1;
    if (s < 31) {
      k3b_stage(aBase + (size_t)(s + 1) * (256 * 64),
                bBase + (size_t)(s + 1) * (NROWS * 64),
                lA[cur ^ 1], lB[cur ^ 1], wave, lane);
      K3_WAITV(6);
    } else {
      K3_WAITV(0);
    }
    __builtin_amdgcn_s_barrier();
    k3b_compute(lA[cur], lB[cur], acc, wm, wn, l15, l4);
    __builtin_amdgcn_s_barrier();
  }

  // D[n][m] -> partial[m][n] (mapping verified r2-r8)
#pragma unroll
  for (int ni = 0; ni < 4; ++ni)
#pragma unroll
    for (int mi = 0; mi < 4; ++mi) {
      int n = wn * 64 + ni * 16 + l4 * 4;
      int m = m0 + wm * 64 + mi * 16 + l15;
      *(f32x4*)(outp + (size_t)m * DIM + n) = acc[ni][mi];
    }
}

// ---------------- K4: sum 4 partials + hyperbolic chain #2 -> d_out ----------------
__global__ __launch_bounds__(256)
void hgcn_k4(const float* __restrict__ pbase, size_t pstride,
             float* __restrict__ out) {
  const float maxn = 1.0f - 1e-5f;
  int t = threadIdx.x;
  int wave = t >> 6, lane = t & 63;
  size_t row = (size_t)blockIdx.x * 4 + wave;
  int c0 = lane * 4;
  size_t off = row * DIM + c0;
  float sx = 0.f, sy = 0.f, sz = 0.f, sw = 0.f;
#pragma unroll
  for (int i = 0; i < KSPLIT; ++i) {
    float4 v = *(const float4*)(pbase + (size_t)i * pstride + off);
    sx += v.x; sy += v.y; sz += v.z; sw += v.w;
  }
  float un2 = wsum(sx * sx + sy * sy + sz * sz + sw * sw);
  float un = fmaxf(sqrtf(un2), 1e-15f);
  float t1 = tanhf(un) / un;
  float hx = sx * t1, hy = sy * t1, hz = sz * t1, hw = sw * t1;
  float hn = fmaxf(fabsf(t1) * un, 1e-15f);
  float s1 = hn > maxn ? maxn / hn : 1.0f;
  hx *= s1; hy *= s1; hz *= s1; hw *= s1;
  float pn = fmaxf(hn * s1, 1e-15f);
  float lf = artanh_c(pn) / pn;
  float rx = fmaxf(hx * lf, 0.0f), ry = fmaxf(hy * lf, 0.0f);
  float rz = fmaxf(hz * lf, 0.0f), rw = fmaxf(hw * lf, 0.0f);
  float rn2 = wsum(rx * rx + ry * ry + rz * rz + rw * rw);
  float rn = fmaxf(sqrtf(rn2), 1e-15f);
  float t2 = tanhf(rn) / rn;
  float ox = rx * t2, oy = ry * t2, oz = rz * t2, ow = rw * t2;
  float on = fmaxf(fabsf(t2) * rn, 1e-15f);
  float s3 = on > maxn ? maxn / on : 1.0f;
  float4 o = {ox * s3, oy * s3, oz * s3, ow * s3};
  *(float4*)(out + off) = o;
}

extern "C" void kernel_launch(void* const* d_in, const int* in_sizes, int n_in,
                              void* d_out, int out_size, void* d_ws, size_t ws_size,
                              hipStream_t stream) {
  const float* x = (const float*)d_in[0];
  const float* adj = (const float*)d_in[1];
  const float* wgt = (const float*)d_in[2];
  const float* bias = (const float*)d_in[3];
  float* out = (float*)d_out;
  char* ws = (char*)d_ws;
  float* mx = (float*)ws;                        // [0, 8MB)
  u16* xtTp = (u16*)(ws + ((size_t)8 << 20));    // [8, 12MB)
  u16* adjT = (u16*)(ws + ((size_t)12 << 20));   // [12, 140MB)
  float* pbase = (float*)(ws + ((size_t)140 << 20)); // [140, 172MB)

  hipLaunchKernelGGL(hgcn_k1, dim3(128, 4), dim3(256), 0, stream, x, wgt, mx);
  hipLaunchKernelGGL(hgcn_k2, dim3(128), dim3(256), 0, stream, x, mx, bias, xtTp);
  hipLaunchKernelGGL(hgcn_k3a, dim3(512), dim3(256), 0, stream, adj, adjT);
  hipLaunchKernelGGL(hgcn_k3b, dim3(256), dim3(512), 0, stream, adjT, xtTp, pbase);
  hipLaunchKernelGGL(hgcn_k4, dim3(2048), dim3(256), 0, stream,
                     pbase, (size_t)NROWS * DIM, out);
}